// Round 10
// baseline (790.562 us; speedup 1.0000x reference)
//
#include <hip/hip_runtime.h>
#include <stdint.h>

// Problem constants
#define NB 4096
#define NT 200
#define NE 64
// attention: 4E=256 -> 64 -> 32 -> 1 ; final MLP: 272 -> 256 -> 128 -> 1
//
// ABI (proven by R2-R9 elimination + detectors):
//  - d_in order = reference dict order (identity)
//  - float tensors fp32, int tensors int32, mask int32 0/1
//  - OUTPUT IS FP32 (reference returns jnp.float32; the "bf16" in the
//    harness error label is a hardcoded f-string literal, not the dtype).
//    R0-R9 wrote bf16 ushorts -> half-filled buffer read as fp32 -> the
//    stable ~0.26 absmax. One line, nine rounds.

struct Smem {
    int    hist[NT];
    float  q[NE];
    float4 keys4[NT * 16];   // 51200 B, 16B aligned
    float  w2[NE * 32];      // 8192 B
    float  b2[32];
    float  wo[32];
    float  scores[NT];       // reused as softmax weights
    float  ip[4 * NE];
    float  red_a[4];
    float  red_b[4];
    float  row[272];         // mlp input row
    float  mh1[256];
    float  mp2[256];
    float  mh2[128];
};                            // ~66 KB -> 2 blocks/CU

__global__ __launch_bounds__(256)
void din_fused(const int* __restrict__ target_item,
               const int* __restrict__ history_items,
               const int* __restrict__ history_mask,
               const int* __restrict__ sparse_features,
               const float* __restrict__ dense_features,
               const float* __restrict__ item_table,
               const float* __restrict__ user_table,
               const float* __restrict__ ctx_table,
               const float* __restrict__ att_w1,
               const float* __restrict__ att_b1,
               const float* __restrict__ att_w2,
               const float* __restrict__ att_b2,
               const float* __restrict__ att_wo,
               const float* __restrict__ att_bo,
               const float* __restrict__ mlp_w1,
               const float* __restrict__ mlp_b1,
               const float* __restrict__ mlp_w2,
               const float* __restrict__ mlp_b2,
               const float* __restrict__ out_w,
               const float* __restrict__ out_b,
               float* __restrict__ out)
{
    __shared__ Smem sm;

    const int b   = blockIdx.x;
    const int tid = threadIdx.x;
    const int j   = tid & 63;   // lane within wave
    const int wv  = tid >> 6;   // wave id (0..3)

    // ---- phase 0: stage small per-b data -------------------------------
    if (tid < NT) sm.hist[tid] = history_items[b * NT + tid];
    if (tid < NE) sm.q[tid] = item_table[(size_t)target_item[b] * NE + tid];
    for (int i = tid; i < NE * 32; i += 256) sm.w2[i] = att_w2[i];
    if (tid < 32) { sm.b2[tid] = att_b2[tid]; sm.wo[tid] = att_wo[tid]; }
    const float bo = att_bo[0];
    __syncthreads();

    // ---- phase 1: gather keys into LDS ---------------------------------
    {
        const float4* it4 = (const float4*)item_table;
        for (int i = tid; i < NT * 16; i += 256) {
            const int t = i >> 4, e4 = i & 15;
            sm.keys4[t * 16 + e4] = it4[(size_t)sm.hist[t] * 16 + e4];
        }
    }

    // ---- phase 1b: W_eff column j + effective bias (per-thread regs) ---
    // attn_in = [k, q, k-q, k*q] @ w1 factorizes (q row-constant):
    // h1[j] = relu( sum_e k_e*(w1[e,j]+w1[128+e,j]+q_e*w1[192+e,j])
    //              + b1[j] + sum_e q_e*(w1[64+e,j]-w1[128+e,j]) )
    float weff[NE];
    float bias_eff = att_b1[j];
#pragma unroll
    for (int e = 0; e < NE; ++e) {
        const float qe = sm.q[e];
        const float A  = att_w1[(size_t)(e)       * NE + j];
        const float Bv = att_w1[(size_t)(64 + e)  * NE + j];
        const float C  = att_w1[(size_t)(128 + e) * NE + j];
        const float D  = att_w1[(size_t)(192 + e) * NE + j];
        weff[e] = A + C + qe * D;
        bias_eff += qe * (Bv - C);
    }
    __syncthreads();

    // ---- phase 3: scores for all t (wave wv handles t = tb+wv) ---------
    for (int tb = 0; tb < NT; tb += 4) {
        const int t = tb + wv;
        float acc = bias_eff;
#pragma unroll
        for (int e4 = 0; e4 < 16; ++e4) {
            const float4 kv = sm.keys4[t * 16 + e4];   // wave-broadcast read
            acc += kv.x * weff[e4 * 4 + 0];
            acc += kv.y * weff[e4 * 4 + 1];
            acc += kv.z * weff[e4 * 4 + 2];
            acc += kv.w * weff[e4 * 4 + 3];
        }
        const float h1v = fmaxf(acc, 0.f);

        // layer 2: 32 outputs, 64-deep dot split across half-waves (shfl handoff)
        const int o2 = j & 31, half = j >> 5;
        float acc2 = 0.f;
#pragma unroll
        for (int kk = 0; kk < 32; ++kk) {
            const int k = half * 32 + kk;
            acc2 += __shfl(h1v, k, 64) * sm.w2[k * 32 + o2];
        }
        acc2 += __shfl_down(acc2, 32, 64);

        // layer 3 on lanes < 32, then 32-lane reduce
        float sc = 0.f;
        if (j < 32) {
            const float h2 = fmaxf(acc2 + sm.b2[o2], 0.f);
            sc = h2 * sm.wo[o2];
        }
        sc += __shfl_xor(sc, 16);
        sc += __shfl_xor(sc, 8);
        sc += __shfl_xor(sc, 4);
        sc += __shfl_xor(sc, 2);
        sc += __shfl_xor(sc, 1);
        if (j == 0) {
            const float s = sc + bo;
            sm.scores[t] = (history_mask[(size_t)b * NT + t] != 0) ? s : -1e9f;
        }
    }
    __syncthreads();

    // ---- phase 4: softmax over t ---------------------------------------
    const float v = (tid < NT) ? sm.scores[tid] : -INFINITY;
    float m = v;
#pragma unroll
    for (int s = 32; s; s >>= 1) m = fmaxf(m, __shfl_xor(m, s));
    if (j == 0) sm.red_a[wv] = m;
    __syncthreads();
    const float mx = fmaxf(fmaxf(sm.red_a[0], sm.red_a[1]), fmaxf(sm.red_a[2], sm.red_a[3]));
    const float ex = (tid < NT) ? expf(v - mx) : 0.f;
    float ssum = ex;
#pragma unroll
    for (int s = 32; s; s >>= 1) ssum += __shfl_xor(ssum, s);
    if (j == 0) sm.red_b[wv] = ssum;
    __syncthreads();
    const float total = sm.red_b[0] + sm.red_b[1] + sm.red_b[2] + sm.red_b[3];
    if (tid < NT) sm.scores[tid] = ex / total;   // now softmax weights
    __syncthreads();

    // ---- phase 5: interest[e] = sum_t w[t] * keys[t][e] ----------------
    {
        const float* kf = (const float*)sm.keys4;
        float part = 0.f;
        for (int t = wv; t < NT; t += 4)
            part += sm.scores[t] * kf[t * NE + j];
        sm.ip[wv * NE + j] = part;
    }
    __syncthreads();

    // ---- phase 6: build mlp row [user, ctx, q, interest, dense] --------
    if (tid < NE) {
        const float inter = sm.ip[tid] + sm.ip[64 + tid] + sm.ip[128 + tid] + sm.ip[192 + tid];
        sm.row[0 + tid]   = user_table[(size_t)sparse_features[b * 2 + 0] * NE + tid];
        sm.row[64 + tid]  = ctx_table[(size_t)sparse_features[b * 2 + 1] * NE + tid];
        sm.row[128 + tid] = sm.q[tid];
        sm.row[192 + tid] = inter;
    } else if (tid >= 64 && tid < 80) {
        sm.row[256 + (tid - 64)] = dense_features[(size_t)b * 16 + (tid - 64)];
    }
    __syncthreads();

    // ---- phase 7: MLP layer 1: 272 -> 256 ------------------------------
    {
        float acc = mlp_b1[tid];
        for (int k = 0; k < 272; ++k)
            acc += sm.row[k] * mlp_w1[(size_t)k * 256 + tid];
        sm.mh1[tid] = fmaxf(acc, 0.f);
    }
    __syncthreads();

    // ---- phase 8: MLP layer 2: 256 -> 128 (K split over 2 halves) ------
    {
        const int o = tid & 127, half = tid >> 7;
        float acc = 0.f;
        for (int kk = 0; kk < 128; ++kk) {
            const int k = half * 128 + kk;
            acc += sm.mh1[k] * mlp_w2[(size_t)k * 128 + o];
        }
        sm.mp2[half * 128 + o] = acc;
    }
    __syncthreads();
    if (tid < 128)
        sm.mh2[tid] = fmaxf(sm.mp2[tid] + sm.mp2[128 + tid] + mlp_b2[tid], 0.f);
    __syncthreads();

    // ---- phase 9: output: 128 -> 1 (wave 0), FP32 STORE ----------------
    if (tid < 64) {
        float a = sm.mh2[tid]      * out_w[tid]
                + sm.mh2[64 + tid] * out_w[64 + tid];
        a += __shfl_xor(a, 32);
        a += __shfl_xor(a, 16);
        a += __shfl_xor(a, 8);
        a += __shfl_xor(a, 4);
        a += __shfl_xor(a, 2);
        a += __shfl_xor(a, 1);
        if (tid == 0) out[b] = a + out_b[0];
    }
}

// ---------------------------------------------------------------------------
extern "C" void kernel_launch(void* const* d_in, const int* in_sizes, int n_in,
                              void* d_out, int out_size, void* d_ws, size_t ws_size,
                              hipStream_t stream)
{
    din_fused<<<NB, 256, 0, stream>>>(
        (const int*)d_in[0],      // target_item
        (const int*)d_in[1],      // history_items
        (const int*)d_in[2],      // history_mask
        (const int*)d_in[3],      // sparse_features
        (const float*)d_in[4],    // dense_features
        (const float*)d_in[5],    // item_table
        (const float*)d_in[6],    // user_table
        (const float*)d_in[7],    // ctx_table
        (const float*)d_in[8],  (const float*)d_in[9],   // att_w1, att_b1
        (const float*)d_in[10], (const float*)d_in[11],  // att_w2, att_b2
        (const float*)d_in[12], (const float*)d_in[13],  // att_wo, att_bo
        (const float*)d_in[14], (const float*)d_in[15],  // mlp_w1, mlp_b1
        (const float*)d_in[16], (const float*)d_in[17],  // mlp_w2, mlp_b2
        (const float*)d_in[18], (const float*)d_in[19],  // out_w, out_b
        (float*)d_out);
}